// Round 15
// baseline (234.010 us; speedup 1.0000x reference)
//
#include <hip/hip_runtime.h>
#include <cstdint>
#include <cstddef>

#define D_MODEL 1024
#define D_STATE 64
#define SEQ     4096
#define BATCH   2
#define MROWS   (BATCH*SEQ)   // 8192 rows of activations

typedef __bf16 bf16x8 __attribute__((ext_vector_type(8)));
typedef float  f32x4  __attribute__((ext_vector_type(4)));
typedef unsigned short u16;
typedef unsigned int   u32;

union BF8 { bf16x8 v; uint4 q; u16 e[8]; };

__device__ __forceinline__ u16 f2bf(float x) {
    u32 u = __float_as_uint(x);
    u32 r = u + 0x7FFFu + ((u >> 16) & 1u);   // RNE on bf16 boundary
    return (u16)(r >> 16);
}
__device__ __forceinline__ float bf2f(u16 h) {
    return __uint_as_float(((u32)h) << 16);
}
__device__ __forceinline__ uint4 pack8u(const u16* e) {
    return make_uint4((u32)e[0] | ((u32)e[1] << 16), (u32)e[2] | ((u32)e[3] << 16),
                      (u32)e[4] | ((u32)e[5] << 16), (u32)e[6] | ((u32)e[7] << 16));
}

// async global->LDS, 16B per lane. LDS dest is wave-uniform base + lane*16.
__device__ __forceinline__ void async16(const void* g, void* l) {
    __builtin_amdgcn_global_load_lds(
        (const __attribute__((address_space(1))) unsigned int*)(uintptr_t)g,
        (__attribute__((address_space(3))) unsigned int*)(uintptr_t)l,
        16, 0, 0);
}

// ---------------------------------------------------------------------------
// prep: flat fp32 -> bf16 convert over [ x | Win | Wout ] -> [ Ax | Bw1 | Bw2 ].
// (unchanged — verified)
// ---------------------------------------------------------------------------
__global__ __launch_bounds__(256) void prep_kernel(
    const float* __restrict__ x, const float* __restrict__ Win,
    const float* __restrict__ Wout,
    u16* __restrict__ Ax, u16* __restrict__ Bw1, u16* __restrict__ Bw2)
{
    const size_t base = (size_t)blockIdx.x * 4096 + threadIdx.x * 4;
    const float* src; u16* dst; size_t off;
    if (base < 8388608)        { src = x;    dst = Ax;  off = base; }
    else if (base < 9437184)   { src = Win;  dst = Bw1; off = base - 8388608; }
    else                       { src = Wout; dst = Bw2; off = base - 9437184; }
    #pragma unroll
    for (int i = 0; i < 4; ++i) {
        const float4 v = *reinterpret_cast<const float4*>(src + off + i * 1024);
        *reinterpret_cast<uint2*>(dst + off + i * 1024) =
            make_uint2((u32)f2bf(v.x) | ((u32)f2bf(v.y) << 16),
                       (u32)f2bf(v.z) | ((u32)f2bf(v.w) << 16));
    }
}

// ---------------------------------------------------------------------------
// gemm_bt: out[m,c] = sum_k A[m,k]*Bm[c,k] + bias[c], K=1024 bf16.
// (verified round-0 structure — unchanged this round)
// MODE 0: fp32 [m][1024] coalesced store. MODE 1: transposed store into
// ut[b][c][l] via per-wave LDS patch.
// ---------------------------------------------------------------------------
template<int MODE>
__global__ __launch_bounds__(256) void gemm_bt(
    const u16* __restrict__ A, const u16* __restrict__ Bm,
    const float* __restrict__ bias, float* __restrict__ out)
{
    __shared__ __align__(16) u16 As[2][128 * 64];
    __shared__ __align__(16) u16 Bs[2][128 * 64];
    const int bid  = blockIdx.x;
    const int slot = bid >> 3;
    const int m0 = ((bid & 7) * 8 + (slot >> 3)) * 128;   // XCD-grouped m-strips
    const int n0 = (slot & 7) * 128;
    const int tid = threadIdx.x;
    const int wave = tid >> 6, lane = tid & 63;
    const int wm = wave >> 1, wn = wave & 1;
    const int qm = lane & 15, qk = lane >> 4;
    f32x4 acc[4][4] = {};

    auto stage = [&](u16* Ad, u16* Bd, int k0) {
        #pragma unroll
        for (int it = 0; it < 4; ++it) {
            const int c   = it * 256 + tid;          // chunk 0..1023 (16B each)
            const int row = c >> 3, col = (c & 7) * 8;
            const int ldsbase = (it * 256 + wave * 64) * 8;   // wave-uniform
            async16(&A[(size_t)(m0 + row) * D_MODEL + k0 + col], Ad + ldsbase);
            async16(&Bm[(size_t)(n0 + row) * D_MODEL + k0 + col], Bd + ldsbase);
        }
    };
    auto compute = [&](const u16* As_, const u16* Bs_) {
        #pragma unroll
        for (int kk = 0; kk < 2; ++kk) {
            bf16x8 af[4], bg[4];
            #pragma unroll
            for (int i = 0; i < 4; ++i) {
                af[i] = *reinterpret_cast<const bf16x8*>(&As_[(wm*64 + i*16 + qm)*64 + kk*32 + qk*8]);
                bg[i] = *reinterpret_cast<const bf16x8*>(&Bs_[(wn*64 + i*16 + qm)*64 + kk*32 + qk*8]);
            }
            #pragma unroll
            for (int i = 0; i < 4; ++i)
                #pragma unroll
                for (int j = 0; j < 4; ++j)
                    acc[i][j] = __builtin_amdgcn_mfma_f32_16x16x32_bf16(af[i], bg[j], acc[i][j], 0, 0, 0);
        }
    };

    stage(As[0], Bs[0], 0);
    __syncthreads();
    #pragma unroll 1
    for (int kp = 0; kp < 7; ++kp) {
        stage(As[1], Bs[1], 128 * kp + 64);
        compute(As[0], Bs[0]);
        __syncthreads();
        stage(As[0], Bs[0], 128 * kp + 128);
        compute(As[1], Bs[1]);
        __syncthreads();
    }
    stage(As[1], Bs[1], 960);
    compute(As[0], Bs[0]);      // k=896
    __syncthreads();
    compute(As[1], Bs[1]);      // k=960

    // C/D layout: col = lane&15, row = (lane>>4)*4 + reg  [m89/m91-verified]
    if (MODE == 0) {
        #pragma unroll
        for (int i = 0; i < 4; ++i) {
            const int r0 = m0 + wm*64 + i*16 + qk*4;
            #pragma unroll
            for (int j = 0; j < 4; ++j) {
                const int c = n0 + wn*64 + j*16 + qm;
                const float bv = bias[c];
                #pragma unroll
                for (int reg = 0; reg < 4; ++reg)
                    out[(size_t)(r0 + reg) * D_MODEL + c] = acc[i][j][reg] + bv;
            }
        }
    } else {
        // As[0..] aliased as fp32 transpose patch (16.6KB; spills 256B into
        // As[1] which is dead after the final compute).
        float* Tt = reinterpret_cast<float*>(&As[0][0]);   // 4 waves x 16x65 fp32
        float* T = &Tt[wave * 16 * 65];
        float bvj[4];
        #pragma unroll
        for (int j = 0; j < 4; ++j) bvj[j] = bias[n0 + wn*64 + j*16 + qm];
        const int dcol = n0 + wn*64 + lane;            // read-phase column (d)
        #pragma unroll
        for (int i = 0; i < 4; ++i) {
            #pragma unroll
            for (int j = 0; j < 4; ++j)
                #pragma unroll
                for (int reg = 0; reg < 4; ++reg)
                    T[(qk*4 + reg) * 65 + j*16 + qm] = acc[i][j][reg] + bvj[j];
            __builtin_amdgcn_wave_barrier();
            float4 o[4];
            #pragma unroll
            for (int t4 = 0; t4 < 4; ++t4)
                o[t4] = make_float4(T[(t4*4 + 0) * 65 + lane], T[(t4*4 + 1) * 65 + lane],
                                    T[(t4*4 + 2) * 65 + lane], T[(t4*4 + 3) * 65 + lane]);
            const int r0 = m0 + wm*64 + i*16;
            const int bb = r0 >> 12, l0 = r0 & (SEQ - 1);
            float* dst = &out[((size_t)(bb * D_MODEL + dcol)) * SEQ + l0];
            #pragma unroll
            for (int t4 = 0; t4 < 4; ++t4)
                reinterpret_cast<float4*>(dst)[t4] = o[t4];
            __builtin_amdgcn_wave_barrier();
        }
    }
}

// ---------------------------------------------------------------------------
// scan2: MFMA chunked scan, fused in-LDS table build. 1024 blocks x 128 thr.
// (y-bf16 epilogue — verified R9)
// ---------------------------------------------------------------------------
__global__ __launch_bounds__(128) void scan2_kernel(
    float* __restrict__ ut, const float* __restrict__ A_log,
    const float* __restrict__ Bp, const float* __restrict__ Cp,
    const float* __restrict__ dtp, const float* __restrict__ Dpv)
{
    __shared__ __align__(16) u16 KT_s[64 * 64];
    __shared__ __align__(16) u16 RA_s[64 * 64];
    __shared__ __align__(16) u16 P2_s[64 * 64];
    __shared__ __align__(16) u16 SH[2][64 * 64];   // scratch during build; S/H after
    const int d = blockIdx.x, tid = threadIdx.x;
    const int w = tid >> 6, lane = tid & 63;
    const int qm = lane & 15, qk = lane >> 4;

    const float dt_d  = dtp[d];
    const float logdA = -expf(-A_log[d * D_STATE + lane]) * dt_d;
    const float r     = expf(logdA);
    const float dBn   = Bp[d * D_STATE + lane] * dt_d;
    const float Cv    = Cp[d * D_STATE + lane];
    const float rTn   = expf(logdA * 64.0f);
    const float Dpd   = Dpv[d];

    float* ug = ut + ((size_t)(w * D_MODEL + d)) * SEQ;

    // fp32 scratch inside SH (dead until S-phase): dB[64] | w[64] | k[64]
    float* dB_sh = reinterpret_cast<float*>(&SH[0][0]);
    float* w_sh  = dB_sh + 64;
    float* k_sh  = dB_sh + 128;

    // ---- U B-fragments (global fp32 -> hi/lo bf16), kk 0..1 = hi, 2..3 = lo
    bf16x8 Uf[4][4];
    #pragma unroll
    for (int ct = 0; ct < 4; ++ct) {
        const float* src = ug + (ct * 16 + qm) * 64;
        #pragma unroll
        for (int jb = 0; jb < 2; ++jb) {
            const float4 v0 = *reinterpret_cast<const float4*>(src + jb * 32 + qk * 8);
            const float4 v1 = *reinterpret_cast<const float4*>(src + jb * 32 + qk * 8 + 4);
            const float fv[8] = {v0.x, v0.y, v0.z, v0.w, v1.x, v1.y, v1.z, v1.w};
            BF8 hi, lo;
            #pragma unroll
            for (int i = 0; i < 8; ++i) {
                hi.e[i] = f2bf(fv[i]);
                lo.e[i] = f2bf(fv[i] - bf2f(hi.e[i]));
            }
            Uf[ct][jb]     = hi.v;
            Uf[ct][jb + 2] = lo.v;
        }
    }

    // ---- table build phase 1
    if (w == 0) {
        dB_sh[lane] = dBn;
        w_sh[lane]  = Cv * dBn;
        for (int o = 0; o < 8; ++o) {   // RA row n=lane: r^(63-j), j ascending
            float tmp[8];
            tmp[7] = expf(logdA * (float)(63 - (o * 8 + 7)));
            #pragma unroll
            for (int i = 6; i >= 0; --i) tmp[i] = tmp[i + 1] * r;
            u16 e[8];
            #pragma unroll
            for (int i = 0; i < 8; ++i) e[i] = f2bf(tmp[i]);
            *reinterpret_cast<uint4*>(&RA_s[lane * 64 + o * 8]) = pack8u(e);
        }
    } else {
        float p = Cv;                   // P2 column n=lane: C r^{t+1}
        for (int t = 0; t < 64; ++t) { p *= r; P2_s[t * 64 + lane] = f2bf(p); }
    }
    __syncthreads();
    // ---- table build phase 2 (wave0): k from P2, then KT rows
    if (w == 0) {
        float kacc = 0.f;
        if (lane == 0) {
            for (int n = 0; n < 64; ++n) kacc += w_sh[n];
        } else {
            const u16* prow = &P2_s[(lane - 1) * 64];
            for (int o = 0; o < 8; ++o) {
                BF8 p8; p8.q = *reinterpret_cast<const uint4*>(&prow[o * 8]);
                #pragma unroll
                for (int i = 0; i < 8; ++i) kacc += dB_sh[o * 8 + i] * bf2f(p8.e[i]);
            }
        }
        k_sh[lane] = kacc;              // same-wave LDS: in-order visibility
        for (int o = 0; o < 8; ++o) {   // KT row t=lane
            u16 e[8];
            #pragma unroll
            for (int i = 0; i < 8; ++i) {
                const int j = o * 8 + i;
                e[i] = (j <= lane) ? f2bf(k_sh[lane - j]) : (u16)0;
            }
            *reinterpret_cast<uint4*>(&KT_s[lane * 64 + o * 8]) = pack8u(e);
        }
    }
    __syncthreads();

    u16* sh = SH[w];
    {   // ---- S = RA_ext @ U_ext -> SH[w][c][n] bf16
        bf16x8 Af[4][2];
        #pragma unroll
        for (int nt = 0; nt < 4; ++nt)
            #pragma unroll
            for (int jb = 0; jb < 2; ++jb)
                Af[nt][jb] = *reinterpret_cast<const bf16x8*>(
                    &RA_s[(nt * 16 + qm) * 64 + jb * 32 + qk * 8]);
        f32x4 acc[4][4] = {};
        #pragma unroll
        for (int kk = 0; kk < 4; ++kk)
            #pragma unroll
            for (int nt = 0; nt < 4; ++nt)
                #pragma unroll
                for (int ct = 0; ct < 4; ++ct)
                    acc[nt][ct] = __builtin_amdgcn_mfma_f32_16x16x32_bf16(
                        Af[nt][kk & 1], Uf[ct][kk], acc[nt][ct], 0, 0, 0);
        #pragma unroll
        for (int nt = 0; nt < 4; ++nt)
            #pragma unroll
            for (int ct = 0; ct < 4; ++ct) {
                const int c = ct * 16 + qm, nn0 = nt * 16 + qk * 4;
                uint2 pk;
                pk.x = (u32)f2bf(acc[nt][ct][0]) | ((u32)f2bf(acc[nt][ct][1]) << 16);
                pk.y = (u32)f2bf(acc[nt][ct][2]) | ((u32)f2bf(acc[nt][ct][3]) << 16);
                *reinterpret_cast<uint2*>(&sh[c * 64 + nn0]) = pk;
            }
    }
    __syncthreads();

    {   // ---- serial inter-chunk hop, lane=n, batched: 16 reads ahead of chain
        float h = 0.f;
        u16* col = sh + lane;
        for (int b = 0; b < 4; ++b) {
            float sb[16];
            #pragma unroll
            for (int i = 0; i < 16; ++i) sb[i] = bf2f(col[(b * 16 + i) * 64]);
            #pragma unroll
            for (int i = 0; i < 16; ++i) {
                col[(b * 16 + i) * 64] = f2bf(h);
                h = rTn * h + dBn * sb[i];
            }
        }
    }
    __syncthreads();

    {   // ---- Y = KT_ext @ U_ext + P2 @ H ; fold Dp*u skip; write y bf16
        bf16x8 Af[4][2];
        #pragma unroll
        for (int tt = 0; tt < 4; ++tt)
            #pragma unroll
            for (int jb = 0; jb < 2; ++jb)
                Af[tt][jb] = *reinterpret_cast<const bf16x8*>(
                    &KT_s[(tt * 16 + qm) * 64 + jb * 32 + qk * 8]);
        f32x4 acc[4][4] = {};
        #pragma unroll
        for (int kk = 0; kk < 4; ++kk)
            #pragma unroll
            for (int tt = 0; tt < 4; ++tt)
                #pragma unroll
                for (int ct = 0; ct < 4; ++ct)
                    acc[tt][ct] = __builtin_amdgcn_mfma_f32_16x16x32_bf16(
                        Af[tt][kk & 1], Uf[ct][kk], acc[tt][ct], 0, 0, 0);
        bf16x8 Pf[4][2];
        #pragma unroll
        for (int tt = 0; tt < 4; ++tt)
            #pragma unroll
            for (int kb = 0; kb < 2; ++kb)
                Pf[tt][kb] = *reinterpret_cast<const bf16x8*>(
                    &P2_s[(tt * 16 + qm) * 64 + kb * 32 + qk * 8]);
        #pragma unroll
        for (int ct = 0; ct < 4; ++ct)
            #pragma unroll
            for (int kb = 0; kb < 2; ++kb) {
                const bf16x8 Hf = *reinterpret_cast<const bf16x8*>(
                    &sh[(ct * 16 + qm) * 64 + kb * 32 + qk * 8]);
                #pragma unroll
                for (int tt = 0; tt < 4; ++tt)
                    acc[tt][ct] = __builtin_amdgcn_mfma_f32_16x16x32_bf16(
                        Pf[tt][kb], Hf, acc[tt][ct], 0, 0, 0);
            }
        // fold skip: read ALL u fp32 first (no overwrite yet)
        #pragma unroll
        for (int tt = 0; tt < 4; ++tt)
            #pragma unroll
            for (int ct = 0; ct < 4; ++ct) {
                const int c = ct * 16 + qm, t0 = tt * 16 + qk * 4;
                const float4 u4 = *reinterpret_cast<const float4*>(ug + c * 64 + t0);
                acc[tt][ct][0] += Dpd * u4.x;
                acc[tt][ct][1] += Dpd * u4.y;
                acc[tt][ct][2] += Dpd * u4.z;
                acc[tt][ct][3] += Dpd * u4.w;
            }
        __syncthreads();   // drain u reads before the bf16 overwrite of row halves
        u16* yb = reinterpret_cast<u16*>(ug);   // first 8KB of own 16KB row
        #pragma unroll
        for (int tt = 0; tt < 4; ++tt)
            #pragma unroll
            for (int ct = 0; ct < 4; ++ct) {
                const int c = ct * 16 + qm, t0 = tt * 16 + qk * 4;
                uint2 pk;
                pk.x = (u32)f2bf(acc[tt][ct][0]) | ((u32)f2bf(acc[tt][ct][1]) << 16);
                pk.y = (u32)f2bf(acc[tt][ct][2]) | ((u32)f2bf(acc[tt][ct][3]) << 16);
                *reinterpret_cast<uint2*>(&yb[c * 64 + t0]) = pk;
            }
    }
}

// ---------------------------------------------------------------------------
// transpose y bf16 [b][d][l] (packed in first half of ut rows, row stride
// 8192 u16) -> Ax rows [b*L][1024] bf16 for GEMM2. (verified R9)
// ---------------------------------------------------------------------------
__global__ __launch_bounds__(256) void trans_kernel(
    const float* __restrict__ yt, u16* __restrict__ Ax)
{
    __shared__ float T[64 * 68];
    const int b = blockIdx.z, dx = blockIdx.y * 64, lx = blockIdx.x * 64;
    const int tid = threadIdx.x;
    const int t16 = tid >> 4, l16 = tid & 15;
    const u16* yb = reinterpret_cast<const u16*>(yt);
    #pragma unroll
    for (int ii = 0; ii < 4; ++ii) {
        const int dd = ii * 16 + t16;
        const int ll = l16 * 4;
        const uint2 v = *reinterpret_cast<const uint2*>(
            &yb[((size_t)(b * D_MODEL + dx + dd)) * (SEQ * 2) + lx + ll]);
        *reinterpret_cast<float4*>(&T[dd * 68 + ll]) =
            make_float4(bf2f((u16)(v.x & 0xFFFFu)), bf2f((u16)(v.x >> 16)),
                        bf2f((u16)(v.y & 0xFFFFu)), bf2f((u16)(v.y >> 16)));
    }
    __syncthreads();
    #pragma unroll
    for (int ii = 0; ii < 4; ++ii) {
        const int ll = ii * 16 + t16;
        const int dd = l16 * 4;
        float v0 = T[(dd + 0) * 68 + ll], v1 = T[(dd + 1) * 68 + ll];
        float v2 = T[(dd + 2) * 68 + ll], v3 = T[(dd + 3) * 68 + ll];
        const size_t row = (size_t)b * SEQ + lx + ll;
        *reinterpret_cast<uint2*>(Ax + row * D_MODEL + dx + dd) =
            make_uint2((u32)f2bf(v0) | ((u32)f2bf(v1) << 16),
                       (u32)f2bf(v2) | ((u32)f2bf(v3) << 16));
    }
}

// ---------------------------------------------------------------------------
// ATTRIBUTION PROBE 3 (this round only): scan2 launched 3x — 1 real (before
// trans) + 2 dups AFTER trans, where ut is dead (gemm2 reads only Ax, which
// trans already produced). Dup table-build uses only real params (A_log/B/C/
// dt); only the Uf/u4 loads see stale ut bytes — timing-representative
// (fixed loop counts). Output bit-identical.
// Readout: scan2 = (dur_us - 185.6)/2.
// [Ledger: g1+g2 = 53.6 (R12), prep+trans = 18.3 (R13)]
//
// Workspace (60 MB):
//   [0,  24MB)  Ax (16MB used)
//   [24, 56MB)  ut : [b][d][l] fp32 (scan writes y bf16 into row first-halves)
//   [56, 58MB)  Bw1 : Win bf16
//   [58, 60MB)  Bw2 : Wout bf16
// ---------------------------------------------------------------------------
extern "C" void kernel_launch(void* const* d_in, const int* in_sizes, int n_in,
                              void* d_out, int out_size, void* d_ws, size_t ws_size,
                              hipStream_t stream) {
    const float* x     = (const float*)d_in[0];
    const float* Win   = (const float*)d_in[1];
    const float* bin   = (const float*)d_in[2];
    const float* A_log = (const float*)d_in[3];
    const float* Bp    = (const float*)d_in[4];
    const float* Cp    = (const float*)d_in[5];
    const float* Dpv   = (const float*)d_in[6];
    const float* dtp   = (const float*)d_in[7];
    const float* Wout  = (const float*)d_in[8];
    const float* bout  = (const float*)d_in[9];
    float* out = (float*)d_out;

    char* ws = (char*)d_ws;
    u16*   Ax  = (u16*)(ws);
    float* ut  = (float*)(ws + (size_t)25165824);
    u16*   Bw1 = (u16*)(ws + (size_t)58720256);
    u16*   Bw2 = (u16*)(ws + (size_t)60817408);

    prep_kernel<<<2560, 256, 0, stream>>>(x, Win, Wout, Ax, Bw1, Bw2);
    gemm_bt<1><<<512, 256, 0, stream>>>(Ax, Bw1, bin, ut);
    scan2_kernel<<<D_MODEL, 128, 0, stream>>>(ut, A_log, Bp, Cp, dtp, Dpv);
    trans_kernel<<<dim3(SEQ / 64, D_MODEL / 64, BATCH), 256, 0, stream>>>(ut, Ax);
    scan2_kernel<<<D_MODEL, 128, 0, stream>>>(ut, A_log, Bp, Cp, dtp, Dpv);  // probe dup (ut dead)
    scan2_kernel<<<D_MODEL, 128, 0, stream>>>(ut, A_log, Bp, Cp, dtp, Dpv);  // probe dup (ut dead)
    gemm_bt<0><<<512, 256, 0, stream>>>(Ax, Bw2, bout, out);
}

// Round 17
// 196.141 us; speedup vs baseline: 1.1931x; 1.1931x over previous
//
#include <hip/hip_runtime.h>
#include <cstdint>
#include <cstddef>

#define D_MODEL 1024
#define D_STATE 64
#define SEQ     4096
#define BATCH   2
#define MROWS   (BATCH*SEQ)   // 8192 rows of activations

typedef __bf16 bf16x8 __attribute__((ext_vector_type(8)));
typedef float  f32x4  __attribute__((ext_vector_type(4)));
typedef unsigned short u16;
typedef unsigned int   u32;

union BF8 { bf16x8 v; uint4 q; u16 e[8]; };

__device__ __forceinline__ u16 f2bf(float x) {
    u32 u = __float_as_uint(x);
    u32 r = u + 0x7FFFu + ((u >> 16) & 1u);   // RNE on bf16 boundary
    return (u16)(r >> 16);
}
__device__ __forceinline__ float bf2f(u16 h) {
    return __uint_as_float(((u32)h) << 16);
}
__device__ __forceinline__ uint4 pack8u(const u16* e) {
    return make_uint4((u32)e[0] | ((u32)e[1] << 16), (u32)e[2] | ((u32)e[3] << 16),
                      (u32)e[4] | ((u32)e[5] << 16), (u32)e[6] | ((u32)e[7] << 16));
}

// async global->LDS, 16B per lane. LDS dest is wave-uniform base + lane*16.
__device__ __forceinline__ void async16(const void* g, void* l) {
    __builtin_amdgcn_global_load_lds(
        (const __attribute__((address_space(1))) unsigned int*)(uintptr_t)g,
        (__attribute__((address_space(3))) unsigned int*)(uintptr_t)l,
        16, 0, 0);
}

// ---------------------------------------------------------------------------
// prep: flat fp32 -> bf16 convert over [ x | Win | Wout ] -> [ Ax | Bw1 | Bw2 ].
// (unchanged — verified; probe R13: prep+trans = 18.3us, near streaming floor)
// ---------------------------------------------------------------------------
__global__ __launch_bounds__(256) void prep_kernel(
    const float* __restrict__ x, const float* __restrict__ Win,
    const float* __restrict__ Wout,
    u16* __restrict__ Ax, u16* __restrict__ Bw1, u16* __restrict__ Bw2)
{
    const size_t base = (size_t)blockIdx.x * 4096 + threadIdx.x * 4;
    const float* src; u16* dst; size_t off;
    if (base < 8388608)        { src = x;    dst = Ax;  off = base; }
    else if (base < 9437184)   { src = Win;  dst = Bw1; off = base - 8388608; }
    else                       { src = Wout; dst = Bw2; off = base - 9437184; }
    #pragma unroll
    for (int i = 0; i < 4; ++i) {
        const float4 v = *reinterpret_cast<const float4*>(src + off + i * 1024);
        *reinterpret_cast<uint2*>(dst + off + i * 1024) =
            make_uint2((u32)f2bf(v.x) | ((u32)f2bf(v.y) << 16),
                       (u32)f2bf(v.z) | ((u32)f2bf(v.w) << 16));
    }
}

// ---------------------------------------------------------------------------
// gemm_bt (v3b — occupancy experiment, LDS-UB FIX): out[m,c] = sum_k
// A[m,k]*Bm[c,k]+bias, K=1024 bf16. 64x128 tile, BK=32, 4 waves (2m x 2n),
// grid = 1024 = 4 scheduled/CU, LDS 24 KB -> 6-resident/CU headroom.
// R16 FAILED (absmax 1.72): MODE1's transpose patch aliased PAST the 8KB As
// array across separate __shared__ objects (UB; waves 1-3 corrupted). FIX:
// single contiguous LDS array L[12288] u16; As0/As1/Bs0/Bs1 at u16 offsets
// 0/2048/4096/8192; T patch aliases L[0] (16.6KB <= 24KB, one object).
// MFMA k-sequence per output (k=0,32,...,992) identical to verified v2 ->
// bit-identical results. XCD swizzle: bid&7 = XCD, 16 m-strips x 8 n-blocks
// per XCD (2MB A + 2MB B = 4MB L2).
// MODE 0: fp32 [m][1024] store. MODE 1: transposed store into ut[b][c][l]
// via per-wave 16x65 fp32 LDS patch after a block-wide __syncthreads().
// ---------------------------------------------------------------------------
template<int MODE>
__global__ __launch_bounds__(256) void gemm_bt(
    const u16* __restrict__ A, const u16* __restrict__ Bm,
    const float* __restrict__ bias, float* __restrict__ out)
{
    __shared__ __align__(16) u16 L[12288];          // 24 KB total
    u16* const As0 = L;                             // 64x32
    u16* const As1 = L + 2048;
    u16* const Bs0 = L + 4096;                      // 128x32
    u16* const Bs1 = L + 8192;
    const int bid = blockIdx.x;
    const int id  = (bid & 7) * 128 + (bid >> 3);   // XCD-grouped tile id
    const int m0  = (id >> 3) * 64;
    const int n0  = (id & 7) * 128;
    const int tid = threadIdx.x;
    const int wave = tid >> 6, lane = tid & 63;
    const int wm = wave >> 1, wn = wave & 1;        // 2m x 2n wave grid
    const int qm = lane & 15, qk = lane >> 4;
    f32x4 acc[2][4] = {};

    // A tile 64x32 = 256 x 16B chunks (1/thread); B tile 128x32 = 512 (2/thread)
    auto stage = [&](u16* Ad, u16* Bd, int k0) {
        {
            const int c = wave * 64 + lane;          // 0..255
            const int row = c >> 2, col = (c & 3) * 8;
            async16(&A[(size_t)(m0 + row) * D_MODEL + k0 + col], Ad + wave * 512);
        }
        #pragma unroll
        for (int it = 0; it < 2; ++it) {
            const int c = it * 256 + wave * 64 + lane;   // 0..511
            const int row = c >> 2, col = (c & 3) * 8;
            async16(&Bm[(size_t)(n0 + row) * D_MODEL + k0 + col],
                    Bd + (it * 256 + wave * 64) * 8);
        }
    };
    auto compute = [&](const u16* As_, const u16* Bs_) {
        bf16x8 af[2], bg[4];
        #pragma unroll
        for (int i = 0; i < 2; ++i)
            af[i] = *reinterpret_cast<const bf16x8*>(&As_[(wm*32 + i*16 + qm)*32 + qk*8]);
        #pragma unroll
        for (int j = 0; j < 4; ++j)
            bg[j] = *reinterpret_cast<const bf16x8*>(&Bs_[(wn*64 + j*16 + qm)*32 + qk*8]);
        #pragma unroll
        for (int i = 0; i < 2; ++i)
            #pragma unroll
            for (int j = 0; j < 4; ++j)
                acc[i][j] = __builtin_amdgcn_mfma_f32_16x16x32_bf16(af[i], bg[j], acc[i][j], 0, 0, 0);
    };

    stage(As0, Bs0, 0);
    __syncthreads();
    #pragma unroll 1
    for (int kp = 0; kp < 15; ++kp) {
        stage(As1, Bs1, 64 * kp + 32);
        compute(As0, Bs0);
        __syncthreads();
        stage(As0, Bs0, 64 * kp + 64);
        compute(As1, Bs1);
        __syncthreads();
    }
    stage(As1, Bs1, 992);
    compute(As0, Bs0);          // k=960
    __syncthreads();
    compute(As1, Bs1);          // k=992
    __syncthreads();            // all LDS reads done before MODE1 aliases L

    // C/D layout: col = lane&15, row = (lane>>4)*4 + reg  [m89/m91-verified]
    if (MODE == 0) {
        #pragma unroll
        for (int i = 0; i < 2; ++i) {
            const int r0 = m0 + wm*32 + i*16 + qk*4;
            #pragma unroll
            for (int j = 0; j < 4; ++j) {
                const int c = n0 + wn*64 + j*16 + qm;
                const float bv = bias[c];
                #pragma unroll
                for (int reg = 0; reg < 4; ++reg)
                    out[(size_t)(r0 + reg) * D_MODEL + c] = acc[i][j][reg] + bv;
            }
        }
    } else {
        // per-wave fp32 transpose patch: 4 waves x 16x65 fp32 = 16.6 KB,
        // aliased over the dead GEMM LDS — all within the single L object.
        float* Tt = reinterpret_cast<float*>(&L[0]);
        float* T = &Tt[wave * 16 * 65];
        float bvj[4];
        #pragma unroll
        for (int j = 0; j < 4; ++j) bvj[j] = bias[n0 + wn*64 + j*16 + qm];
        const int dcol = n0 + wn*64 + lane;            // read-phase column (d)
        #pragma unroll
        for (int i = 0; i < 2; ++i) {
            #pragma unroll
            for (int j = 0; j < 4; ++j)
                #pragma unroll
                for (int reg = 0; reg < 4; ++reg)
                    T[(qk*4 + reg) * 65 + j*16 + qm] = acc[i][j][reg] + bvj[j];
            __builtin_amdgcn_wave_barrier();
            float4 o[4];
            #pragma unroll
            for (int t4 = 0; t4 < 4; ++t4)
                o[t4] = make_float4(T[(t4*4 + 0) * 65 + lane], T[(t4*4 + 1) * 65 + lane],
                                    T[(t4*4 + 2) * 65 + lane], T[(t4*4 + 3) * 65 + lane]);
            const int r0 = m0 + wm*32 + i*16;
            const int bb = r0 >> 12, l0 = r0 & (SEQ - 1);
            float* dst = &out[((size_t)(bb * D_MODEL + dcol)) * SEQ + l0];
            #pragma unroll
            for (int t4 = 0; t4 < 4; ++t4)
                reinterpret_cast<float4*>(dst)[t4] = o[t4];
            __builtin_amdgcn_wave_barrier();
        }
    }
}

// ---------------------------------------------------------------------------
// scan2: MFMA chunked scan, fused in-LDS table build. 1024 blocks x 128 thr.
// (y-bf16 epilogue — verified R9; probe R15: 24.2us)
// ---------------------------------------------------------------------------
__global__ __launch_bounds__(128) void scan2_kernel(
    float* __restrict__ ut, const float* __restrict__ A_log,
    const float* __restrict__ Bp, const float* __restrict__ Cp,
    const float* __restrict__ dtp, const float* __restrict__ Dpv)
{
    __shared__ __align__(16) u16 KT_s[64 * 64];
    __shared__ __align__(16) u16 RA_s[64 * 64];
    __shared__ __align__(16) u16 P2_s[64 * 64];
    __shared__ __align__(16) u16 SH[2][64 * 64];   // scratch during build; S/H after
    const int d = blockIdx.x, tid = threadIdx.x;
    const int w = tid >> 6, lane = tid & 63;
    const int qm = lane & 15, qk = lane >> 4;

    const float dt_d  = dtp[d];
    const float logdA = -expf(-A_log[d * D_STATE + lane]) * dt_d;
    const float r     = expf(logdA);
    const float dBn   = Bp[d * D_STATE + lane] * dt_d;
    const float Cv    = Cp[d * D_STATE + lane];
    const float rTn   = expf(logdA * 64.0f);
    const float Dpd   = Dpv[d];

    float* ug = ut + ((size_t)(w * D_MODEL + d)) * SEQ;

    // fp32 scratch inside SH (dead until S-phase): dB[64] | w[64] | k[64]
    float* dB_sh = reinterpret_cast<float*>(&SH[0][0]);
    float* w_sh  = dB_sh + 64;
    float* k_sh  = dB_sh + 128;

    // ---- U B-fragments (global fp32 -> hi/lo bf16), kk 0..1 = hi, 2..3 = lo
    bf16x8 Uf[4][4];
    #pragma unroll
    for (int ct = 0; ct < 4; ++ct) {
        const float* src = ug + (ct * 16 + qm) * 64;
        #pragma unroll
        for (int jb = 0; jb < 2; ++jb) {
            const float4 v0 = *reinterpret_cast<const float4*>(src + jb * 32 + qk * 8);
            const float4 v1 = *reinterpret_cast<const float4*>(src + jb * 32 + qk * 8 + 4);
            const float fv[8] = {v0.x, v0.y, v0.z, v0.w, v1.x, v1.y, v1.z, v1.w};
            BF8 hi, lo;
            #pragma unroll
            for (int i = 0; i < 8; ++i) {
                hi.e[i] = f2bf(fv[i]);
                lo.e[i] = f2bf(fv[i] - bf2f(hi.e[i]));
            }
            Uf[ct][jb]     = hi.v;
            Uf[ct][jb + 2] = lo.v;
        }
    }

    // ---- table build phase 1
    if (w == 0) {
        dB_sh[lane] = dBn;
        w_sh[lane]  = Cv * dBn;
        for (int o = 0; o < 8; ++o) {   // RA row n=lane: r^(63-j), j ascending
            float tmp[8];
            tmp[7] = expf(logdA * (float)(63 - (o * 8 + 7)));
            #pragma unroll
            for (int i = 6; i >= 0; --i) tmp[i] = tmp[i + 1] * r;
            u16 e[8];
            #pragma unroll
            for (int i = 0; i < 8; ++i) e[i] = f2bf(tmp[i]);
            *reinterpret_cast<uint4*>(&RA_s[lane * 64 + o * 8]) = pack8u(e);
        }
    } else {
        float p = Cv;                   // P2 column n=lane: C r^{t+1}
        for (int t = 0; t < 64; ++t) { p *= r; P2_s[t * 64 + lane] = f2bf(p); }
    }
    __syncthreads();
    // ---- table build phase 2 (wave0): k from P2, then KT rows
    if (w == 0) {
        float kacc = 0.f;
        if (lane == 0) {
            for (int n = 0; n < 64; ++n) kacc += w_sh[n];
        } else {
            const u16* prow = &P2_s[(lane - 1) * 64];
            for (int o = 0; o < 8; ++o) {
                BF8 p8; p8.q = *reinterpret_cast<const uint4*>(&prow[o * 8]);
                #pragma unroll
                for (int i = 0; i < 8; ++i) kacc += dB_sh[o * 8 + i] * bf2f(p8.e[i]);
            }
        }
        k_sh[lane] = kacc;              // same-wave LDS: in-order visibility
        for (int o = 0; o < 8; ++o) {   // KT row t=lane
            u16 e[8];
            #pragma unroll
            for (int i = 0; i < 8; ++i) {
                const int j = o * 8 + i;
                e[i] = (j <= lane) ? f2bf(k_sh[lane - j]) : (u16)0;
            }
            *reinterpret_cast<uint4*>(&KT_s[lane * 64 + o * 8]) = pack8u(e);
        }
    }
    __syncthreads();

    u16* sh = SH[w];
    {   // ---- S = RA_ext @ U_ext -> SH[w][c][n] bf16
        bf16x8 Af[4][2];
        #pragma unroll
        for (int nt = 0; nt < 4; ++nt)
            #pragma unroll
            for (int jb = 0; jb < 2; ++jb)
                Af[nt][jb] = *reinterpret_cast<const bf16x8*>(
                    &RA_s[(nt * 16 + qm) * 64 + jb * 32 + qk * 8]);
        f32x4 acc[4][4] = {};
        #pragma unroll
        for (int kk = 0; kk < 4; ++kk)
            #pragma unroll
            for (int nt = 0; nt < 4; ++nt)
                #pragma unroll
                for (int ct = 0; ct < 4; ++ct)
                    acc[nt][ct] = __builtin_amdgcn_mfma_f32_16x16x32_bf16(
                        Af[nt][kk & 1], Uf[ct][kk], acc[nt][ct], 0, 0, 0);
        #pragma unroll
        for (int nt = 0; nt < 4; ++nt)
            #pragma unroll
            for (int ct = 0; ct < 4; ++ct) {
                const int c = ct * 16 + qm, nn0 = nt * 16 + qk * 4;
                uint2 pk;
                pk.x = (u32)f2bf(acc[nt][ct][0]) | ((u32)f2bf(acc[nt][ct][1]) << 16);
                pk.y = (u32)f2bf(acc[nt][ct][2]) | ((u32)f2bf(acc[nt][ct][3]) << 16);
                *reinterpret_cast<uint2*>(&sh[c * 64 + nn0]) = pk;
            }
    }
    __syncthreads();

    {   // ---- serial inter-chunk hop, lane=n, batched: 16 reads ahead of chain
        float h = 0.f;
        u16* col = sh + lane;
        for (int b = 0; b < 4; ++b) {
            float sb[16];
            #pragma unroll
            for (int i = 0; i < 16; ++i) sb[i] = bf2f(col[(b * 16 + i) * 64]);
            #pragma unroll
            for (int i = 0; i < 16; ++i) {
                col[(b * 16 + i) * 64] = f2bf(h);
                h = rTn * h + dBn * sb[i];
            }
        }
    }
    __syncthreads();

    {   // ---- Y = KT_ext @ U_ext + P2 @ H ; fold Dp*u skip; write y bf16
        bf16x8 Af[4][2];
        #pragma unroll
        for (int tt = 0; tt < 4; ++tt)
            #pragma unroll
            for (int jb = 0; jb < 2; ++jb)
                Af[tt][jb] = *reinterpret_cast<const bf16x8*>(
                    &KT_s[(tt * 16 + qm) * 64 + jb * 32 + qk * 8]);
        f32x4 acc[4][4] = {};
        #pragma unroll
        for (int kk = 0; kk < 4; ++kk)
            #pragma unroll
            for (int tt = 0; tt < 4; ++tt)
                #pragma unroll
                for (int ct = 0; ct < 4; ++ct)
                    acc[tt][ct] = __builtin_amdgcn_mfma_f32_16x16x32_bf16(
                        Af[tt][kk & 1], Uf[ct][kk], acc[tt][ct], 0, 0, 0);
        bf16x8 Pf[4][2];
        #pragma unroll
        for (int tt = 0; tt < 4; ++tt)
            #pragma unroll
            for (int kb = 0; kb < 2; ++kb)
                Pf[tt][kb] = *reinterpret_cast<const bf16x8*>(
                    &P2_s[(tt * 16 + qm) * 64 + kb * 32 + qk * 8]);
        #pragma unroll
        for (int ct = 0; ct < 4; ++ct)
            #pragma unroll
            for (int kb = 0; kb < 2; ++kb) {
                const bf16x8 Hf = *reinterpret_cast<const bf16x8*>(
                    &sh[(ct * 16 + qm) * 64 + kb * 32 + qk * 8]);
                #pragma unroll
                for (int tt = 0; tt < 4; ++tt)
                    acc[tt][ct] = __builtin_amdgcn_mfma_f32_16x16x32_bf16(
                        Pf[tt][kb], Hf, acc[tt][ct], 0, 0, 0);
            }
        // fold skip: read ALL u fp32 first (no overwrite yet)
        #pragma unroll
        for (int tt = 0; tt < 4; ++tt)
            #pragma unroll
            for (int ct = 0; ct < 4; ++ct) {
                const int c = ct * 16 + qm, t0 = tt * 16 + qk * 4;
                const float4 u4 = *reinterpret_cast<const float4*>(ug + c * 64 + t0);
                acc[tt][ct][0] += Dpd * u4.x;
                acc[tt][ct][1] += Dpd * u4.y;
                acc[tt][ct][2] += Dpd * u4.z;
                acc[tt][ct][3] += Dpd * u4.w;
            }
        __syncthreads();   // drain u reads before the bf16 overwrite of row halves
        u16* yb = reinterpret_cast<u16*>(ug);   // first 8KB of own 16KB row
        #pragma unroll
        for (int tt = 0; tt < 4; ++tt)
            #pragma unroll
            for (int ct = 0; ct < 4; ++ct) {
                const int c = ct * 16 + qm, t0 = tt * 16 + qk * 4;
                uint2 pk;
                pk.x = (u32)f2bf(acc[tt][ct][0]) | ((u32)f2bf(acc[tt][ct][1]) << 16);
                pk.y = (u32)f2bf(acc[tt][ct][2]) | ((u32)f2bf(acc[tt][ct][3]) << 16);
                *reinterpret_cast<uint2*>(&yb[c * 64 + t0]) = pk;
            }
    }
}

// ---------------------------------------------------------------------------
// transpose y bf16 [b][d][l] (packed in first half of ut rows, row stride
// 8192 u16) -> Ax rows [b*L][1024] bf16 for GEMM2. (verified R9)
// ---------------------------------------------------------------------------
__global__ __launch_bounds__(256) void trans_kernel(
    const float* __restrict__ yt, u16* __restrict__ Ax)
{
    __shared__ float T[64 * 68];
    const int b = blockIdx.z, dx = blockIdx.y * 64, lx = blockIdx.x * 64;
    const int tid = threadIdx.x;
    const int t16 = tid >> 4, l16 = tid & 15;
    const u16* yb = reinterpret_cast<const u16*>(yt);
    #pragma unroll
    for (int ii = 0; ii < 4; ++ii) {
        const int dd = ii * 16 + t16;
        const int ll = l16 * 4;
        const uint2 v = *reinterpret_cast<const uint2*>(
            &yb[((size_t)(b * D_MODEL + dx + dd)) * (SEQ * 2) + lx + ll]);
        *reinterpret_cast<float4*>(&T[dd * 68 + ll]) =
            make_float4(bf2f((u16)(v.x & 0xFFFFu)), bf2f((u16)(v.x >> 16)),
                        bf2f((u16)(v.y & 0xFFFFu)), bf2f((u16)(v.y >> 16)));
    }
    __syncthreads();
    #pragma unroll
    for (int ii = 0; ii < 4; ++ii) {
        const int ll = ii * 16 + t16;
        const int dd = l16 * 4;
        float v0 = T[(dd + 0) * 68 + ll], v1 = T[(dd + 1) * 68 + ll];
        float v2 = T[(dd + 2) * 68 + ll], v3 = T[(dd + 3) * 68 + ll];
        const size_t row = (size_t)b * SEQ + lx + ll;
        *reinterpret_cast<uint2*>(Ax + row * D_MODEL + dx + dd) =
            make_uint2((u32)f2bf(v0) | ((u32)f2bf(v1) << 16),
                       (u32)f2bf(v2) | ((u32)f2bf(v3) << 16));
    }
}

// ---------------------------------------------------------------------------
// Ledger (probes R12/R13/R15 @185.6us baseline): g1+g2=53.6, prep+trans=18.3,
// scan2=24.2, fixed harness tax ~89.5. This round: gemm v3b (64x128/BK=32,
// 4+ blocks/CU) with the MODE1 LDS-aliasing UB fixed via single L array.
//
// Workspace (60 MB):
//   [0,  24MB)  Ax (16MB used)
//   [24, 56MB)  ut : [b][d][l] fp32 (scan writes y bf16 into row first-halves)
//   [56, 58MB)  Bw1 : Win bf16
//   [58, 60MB)  Bw2 : Wout bf16
// ---------------------------------------------------------------------------
extern "C" void kernel_launch(void* const* d_in, const int* in_sizes, int n_in,
                              void* d_out, int out_size, void* d_ws, size_t ws_size,
                              hipStream_t stream) {
    const float* x     = (const float*)d_in[0];
    const float* Win   = (const float*)d_in[1];
    const float* bin   = (const float*)d_in[2];
    const float* A_log = (const float*)d_in[3];
    const float* Bp    = (const float*)d_in[4];
    const float* Cp    = (const float*)d_in[5];
    const float* Dpv   = (const float*)d_in[6];
    const float* dtp   = (const float*)d_in[7];
    const float* Wout  = (const float*)d_in[8];
    const float* bout  = (const float*)d_in[9];
    float* out = (float*)d_out;

    char* ws = (char*)d_ws;
    u16*   Ax  = (u16*)(ws);
    float* ut  = (float*)(ws + (size_t)25165824);
    u16*   Bw1 = (u16*)(ws + (size_t)58720256);
    u16*   Bw2 = (u16*)(ws + (size_t)60817408);

    prep_kernel<<<2560, 256, 0, stream>>>(x, Win, Wout, Ax, Bw1, Bw2);
    gemm_bt<1><<<1024, 256, 0, stream>>>(Ax, Bw1, bin, ut);
    scan2_kernel<<<D_MODEL, 128, 0, stream>>>(ut, A_log, Bp, Cp, dtp, Dpv);
    trans_kernel<<<dim3(SEQ / 64, D_MODEL / 64, BATCH), 256, 0, stream>>>(ut, Ax);
    gemm_bt<0><<<1024, 256, 0, stream>>>(Ax, Bw2, bout, out);
}

// Round 18
// 187.097 us; speedup vs baseline: 1.2507x; 1.0483x over previous
//
#include <hip/hip_runtime.h>
#include <cstdint>
#include <cstddef>

#define D_MODEL 1024
#define D_STATE 64
#define SEQ     4096
#define BATCH   2
#define MROWS   (BATCH*SEQ)   // 8192 rows of activations

typedef __bf16 bf16x8 __attribute__((ext_vector_type(8)));
typedef float  f32x4  __attribute__((ext_vector_type(4)));
typedef unsigned short u16;
typedef unsigned int   u32;

union BF8 { bf16x8 v; uint4 q; u16 e[8]; };

__device__ __forceinline__ u16 f2bf(float x) {
    u32 u = __float_as_uint(x);
    u32 r = u + 0x7FFFu + ((u >> 16) & 1u);   // RNE on bf16 boundary
    return (u16)(r >> 16);
}
__device__ __forceinline__ float bf2f(u16 h) {
    return __uint_as_float(((u32)h) << 16);
}
__device__ __forceinline__ uint4 pack8u(const u16* e) {
    return make_uint4((u32)e[0] | ((u32)e[1] << 16), (u32)e[2] | ((u32)e[3] << 16),
                      (u32)e[4] | ((u32)e[5] << 16), (u32)e[6] | ((u32)e[7] << 16));
}

// async global->LDS, 16B per lane. LDS dest is wave-uniform base + lane*16.
__device__ __forceinline__ void async16(const void* g, void* l) {
    __builtin_amdgcn_global_load_lds(
        (const __attribute__((address_space(1))) unsigned int*)(uintptr_t)g,
        (__attribute__((address_space(3))) unsigned int*)(uintptr_t)l,
        16, 0, 0);
}

// ---------------------------------------------------------------------------
// prep: flat fp32 -> bf16 convert over [ x | Win | Wout ] -> [ Ax | Bw1 | Bw2 ].
// (verified; probe R13: prep+trans = 18.3us, near streaming floor)
// ---------------------------------------------------------------------------
__global__ __launch_bounds__(256) void prep_kernel(
    const float* __restrict__ x, const float* __restrict__ Win,
    const float* __restrict__ Wout,
    u16* __restrict__ Ax, u16* __restrict__ Bw1, u16* __restrict__ Bw2)
{
    const size_t base = (size_t)blockIdx.x * 4096 + threadIdx.x * 4;
    const float* src; u16* dst; size_t off;
    if (base < 8388608)        { src = x;    dst = Ax;  off = base; }
    else if (base < 9437184)   { src = Win;  dst = Bw1; off = base - 8388608; }
    else                       { src = Wout; dst = Bw2; off = base - 9437184; }
    #pragma unroll
    for (int i = 0; i < 4; ++i) {
        const float4 v = *reinterpret_cast<const float4*>(src + off + i * 1024);
        *reinterpret_cast<uint2*>(dst + off + i * 1024) =
            make_uint2((u32)f2bf(v.x) | ((u32)f2bf(v.y) << 16),
                       (u32)f2bf(v.z) | ((u32)f2bf(v.w) << 16));
    }
}

// ---------------------------------------------------------------------------
// gemm_bt: out[m,c] = sum_k A[m,k]*Bm[c,k] + bias[c], K=1024 bf16.
// REVERTED to the R9-verified structure (128x128 tile, 4 waves, BK=64,
// double-buffered global_load_lds, XCD-grouped m-strips). Session evidence:
// R0 8-phase T-stack = neutral; R17 64x128/BK=32 occupancy experiment =
// -10.5us (42.3us/dispatch, MfmaUtil 16%, 3.4M bank conflicts) -> this
// structure is the shape-local optimum (~27us/dispatch, R12 probe).
// MODE 0: fp32 [m][1024] coalesced store. MODE 1: transposed store into
// ut[b][c][l] via per-wave LDS patch.
// ---------------------------------------------------------------------------
template<int MODE>
__global__ __launch_bounds__(256) void gemm_bt(
    const u16* __restrict__ A, const u16* __restrict__ Bm,
    const float* __restrict__ bias, float* __restrict__ out)
{
    __shared__ __align__(16) u16 As[2][128 * 64];
    __shared__ __align__(16) u16 Bs[2][128 * 64];
    const int bid  = blockIdx.x;
    const int slot = bid >> 3;
    const int m0 = ((bid & 7) * 8 + (slot >> 3)) * 128;   // XCD-grouped m-strips
    const int n0 = (slot & 7) * 128;
    const int tid = threadIdx.x;
    const int wave = tid >> 6, lane = tid & 63;
    const int wm = wave >> 1, wn = wave & 1;
    const int qm = lane & 15, qk = lane >> 4;
    f32x4 acc[4][4] = {};

    auto stage = [&](u16* Ad, u16* Bd, int k0) {
        #pragma unroll
        for (int it = 0; it < 4; ++it) {
            const int c   = it * 256 + tid;          // chunk 0..1023 (16B each)
            const int row = c >> 3, col = (c & 7) * 8;
            const int ldsbase = (it * 256 + wave * 64) * 8;   // wave-uniform
            async16(&A[(size_t)(m0 + row) * D_MODEL + k0 + col], Ad + ldsbase);
            async16(&Bm[(size_t)(n0 + row) * D_MODEL + k0 + col], Bd + ldsbase);
        }
    };
    auto compute = [&](const u16* As_, const u16* Bs_) {
        #pragma unroll
        for (int kk = 0; kk < 2; ++kk) {
            bf16x8 af[4], bg[4];
            #pragma unroll
            for (int i = 0; i < 4; ++i) {
                af[i] = *reinterpret_cast<const bf16x8*>(&As_[(wm*64 + i*16 + qm)*64 + kk*32 + qk*8]);
                bg[i] = *reinterpret_cast<const bf16x8*>(&Bs_[(wn*64 + i*16 + qm)*64 + kk*32 + qk*8]);
            }
            #pragma unroll
            for (int i = 0; i < 4; ++i)
                #pragma unroll
                for (int j = 0; j < 4; ++j)
                    acc[i][j] = __builtin_amdgcn_mfma_f32_16x16x32_bf16(af[i], bg[j], acc[i][j], 0, 0, 0);
        }
    };

    stage(As[0], Bs[0], 0);
    __syncthreads();
    #pragma unroll 1
    for (int kp = 0; kp < 7; ++kp) {
        stage(As[1], Bs[1], 128 * kp + 64);
        compute(As[0], Bs[0]);
        __syncthreads();
        stage(As[0], Bs[0], 128 * kp + 128);
        compute(As[1], Bs[1]);
        __syncthreads();
    }
    stage(As[1], Bs[1], 960);
    compute(As[0], Bs[0]);      // k=896
    __syncthreads();
    compute(As[1], Bs[1]);      // k=960

    // C/D layout: col = lane&15, row = (lane>>4)*4 + reg  [m89/m91-verified]
    if (MODE == 0) {
        #pragma unroll
        for (int i = 0; i < 4; ++i) {
            const int r0 = m0 + wm*64 + i*16 + qk*4;
            #pragma unroll
            for (int j = 0; j < 4; ++j) {
                const int c = n0 + wn*64 + j*16 + qm;
                const float bv = bias[c];
                #pragma unroll
                for (int reg = 0; reg < 4; ++reg)
                    out[(size_t)(r0 + reg) * D_MODEL + c] = acc[i][j][reg] + bv;
            }
        }
    } else {
        // As[0..] aliased as fp32 transpose patch (16.6KB; spills 256B into
        // As[1] which is dead after the final compute).
        float* Tt = reinterpret_cast<float*>(&As[0][0]);   // 4 waves x 16x65 fp32
        float* T = &Tt[wave * 16 * 65];
        float bvj[4];
        #pragma unroll
        for (int j = 0; j < 4; ++j) bvj[j] = bias[n0 + wn*64 + j*16 + qm];
        const int dcol = n0 + wn*64 + lane;            // read-phase column (d)
        #pragma unroll
        for (int i = 0; i < 4; ++i) {
            #pragma unroll
            for (int j = 0; j < 4; ++j)
                #pragma unroll
                for (int reg = 0; reg < 4; ++reg)
                    T[(qk*4 + reg) * 65 + j*16 + qm] = acc[i][j][reg] + bvj[j];
            __builtin_amdgcn_wave_barrier();
            float4 o[4];
            #pragma unroll
            for (int t4 = 0; t4 < 4; ++t4)
                o[t4] = make_float4(T[(t4*4 + 0) * 65 + lane], T[(t4*4 + 1) * 65 + lane],
                                    T[(t4*4 + 2) * 65 + lane], T[(t4*4 + 3) * 65 + lane]);
            const int r0 = m0 + wm*64 + i*16;
            const int bb = r0 >> 12, l0 = r0 & (SEQ - 1);
            float* dst = &out[((size_t)(bb * D_MODEL + dcol)) * SEQ + l0];
            #pragma unroll
            for (int t4 = 0; t4 < 4; ++t4)
                reinterpret_cast<float4*>(dst)[t4] = o[t4];
            __builtin_amdgcn_wave_barrier();
        }
    }
}

// ---------------------------------------------------------------------------
// scan2: MFMA chunked scan, fused in-LDS table build. 1024 blocks x 128 thr.
// (y-bf16 epilogue — verified R9; probe R15: 24.2us)
// ---------------------------------------------------------------------------
__global__ __launch_bounds__(128) void scan2_kernel(
    float* __restrict__ ut, const float* __restrict__ A_log,
    const float* __restrict__ Bp, const float* __restrict__ Cp,
    const float* __restrict__ dtp, const float* __restrict__ Dpv)
{
    __shared__ __align__(16) u16 KT_s[64 * 64];
    __shared__ __align__(16) u16 RA_s[64 * 64];
    __shared__ __align__(16) u16 P2_s[64 * 64];
    __shared__ __align__(16) u16 SH[2][64 * 64];   // scratch during build; S/H after
    const int d = blockIdx.x, tid = threadIdx.x;
    const int w = tid >> 6, lane = tid & 63;
    const int qm = lane & 15, qk = lane >> 4;

    const float dt_d  = dtp[d];
    const float logdA = -expf(-A_log[d * D_STATE + lane]) * dt_d;
    const float r     = expf(logdA);
    const float dBn   = Bp[d * D_STATE + lane] * dt_d;
    const float Cv    = Cp[d * D_STATE + lane];
    const float rTn   = expf(logdA * 64.0f);
    const float Dpd   = Dpv[d];

    float* ug = ut + ((size_t)(w * D_MODEL + d)) * SEQ;

    // fp32 scratch inside SH (dead until S-phase): dB[64] | w[64] | k[64]
    float* dB_sh = reinterpret_cast<float*>(&SH[0][0]);
    float* w_sh  = dB_sh + 64;
    float* k_sh  = dB_sh + 128;

    // ---- U B-fragments (global fp32 -> hi/lo bf16), kk 0..1 = hi, 2..3 = lo
    bf16x8 Uf[4][4];
    #pragma unroll
    for (int ct = 0; ct < 4; ++ct) {
        const float* src = ug + (ct * 16 + qm) * 64;
        #pragma unroll
        for (int jb = 0; jb < 2; ++jb) {
            const float4 v0 = *reinterpret_cast<const float4*>(src + jb * 32 + qk * 8);
            const float4 v1 = *reinterpret_cast<const float4*>(src + jb * 32 + qk * 8 + 4);
            const float fv[8] = {v0.x, v0.y, v0.z, v0.w, v1.x, v1.y, v1.z, v1.w};
            BF8 hi, lo;
            #pragma unroll
            for (int i = 0; i < 8; ++i) {
                hi.e[i] = f2bf(fv[i]);
                lo.e[i] = f2bf(fv[i] - bf2f(hi.e[i]));
            }
            Uf[ct][jb]     = hi.v;
            Uf[ct][jb + 2] = lo.v;
        }
    }

    // ---- table build phase 1
    if (w == 0) {
        dB_sh[lane] = dBn;
        w_sh[lane]  = Cv * dBn;
        for (int o = 0; o < 8; ++o) {   // RA row n=lane: r^(63-j), j ascending
            float tmp[8];
            tmp[7] = expf(logdA * (float)(63 - (o * 8 + 7)));
            #pragma unroll
            for (int i = 6; i >= 0; --i) tmp[i] = tmp[i + 1] * r;
            u16 e[8];
            #pragma unroll
            for (int i = 0; i < 8; ++i) e[i] = f2bf(tmp[i]);
            *reinterpret_cast<uint4*>(&RA_s[lane * 64 + o * 8]) = pack8u(e);
        }
    } else {
        float p = Cv;                   // P2 column n=lane: C r^{t+1}
        for (int t = 0; t < 64; ++t) { p *= r; P2_s[t * 64 + lane] = f2bf(p); }
    }
    __syncthreads();
    // ---- table build phase 2 (wave0): k from P2, then KT rows
    if (w == 0) {
        float kacc = 0.f;
        if (lane == 0) {
            for (int n = 0; n < 64; ++n) kacc += w_sh[n];
        } else {
            const u16* prow = &P2_s[(lane - 1) * 64];
            for (int o = 0; o < 8; ++o) {
                BF8 p8; p8.q = *reinterpret_cast<const uint4*>(&prow[o * 8]);
                #pragma unroll
                for (int i = 0; i < 8; ++i) kacc += dB_sh[o * 8 + i] * bf2f(p8.e[i]);
            }
        }
        k_sh[lane] = kacc;              // same-wave LDS: in-order visibility
        for (int o = 0; o < 8; ++o) {   // KT row t=lane
            u16 e[8];
            #pragma unroll
            for (int i = 0; i < 8; ++i) {
                const int j = o * 8 + i;
                e[i] = (j <= lane) ? f2bf(k_sh[lane - j]) : (u16)0;
            }
            *reinterpret_cast<uint4*>(&KT_s[lane * 64 + o * 8]) = pack8u(e);
        }
    }
    __syncthreads();

    u16* sh = SH[w];
    {   // ---- S = RA_ext @ U_ext -> SH[w][c][n] bf16
        bf16x8 Af[4][2];
        #pragma unroll
        for (int nt = 0; nt < 4; ++nt)
            #pragma unroll
            for (int jb = 0; jb < 2; ++jb)
                Af[nt][jb] = *reinterpret_cast<const bf16x8*>(
                    &RA_s[(nt * 16 + qm) * 64 + jb * 32 + qk * 8]);
        f32x4 acc[4][4] = {};
        #pragma unroll
        for (int kk = 0; kk < 4; ++kk)
            #pragma unroll
            for (int nt = 0; nt < 4; ++nt)
                #pragma unroll
                for (int ct = 0; ct < 4; ++ct)
                    acc[nt][ct] = __builtin_amdgcn_mfma_f32_16x16x32_bf16(
                        Af[nt][kk & 1], Uf[ct][kk], acc[nt][ct], 0, 0, 0);
        #pragma unroll
        for (int nt = 0; nt < 4; ++nt)
            #pragma unroll
            for (int ct = 0; ct < 4; ++ct) {
                const int c = ct * 16 + qm, nn0 = nt * 16 + qk * 4;
                uint2 pk;
                pk.x = (u32)f2bf(acc[nt][ct][0]) | ((u32)f2bf(acc[nt][ct][1]) << 16);
                pk.y = (u32)f2bf(acc[nt][ct][2]) | ((u32)f2bf(acc[nt][ct][3]) << 16);
                *reinterpret_cast<uint2*>(&sh[c * 64 + nn0]) = pk;
            }
    }
    __syncthreads();

    {   // ---- serial inter-chunk hop, lane=n, batched: 16 reads ahead of chain
        float h = 0.f;
        u16* col = sh + lane;
        for (int b = 0; b < 4; ++b) {
            float sb[16];
            #pragma unroll
            for (int i = 0; i < 16; ++i) sb[i] = bf2f(col[(b * 16 + i) * 64]);
            #pragma unroll
            for (int i = 0; i < 16; ++i) {
                col[(b * 16 + i) * 64] = f2bf(h);
                h = rTn * h + dBn * sb[i];
            }
        }
    }
    __syncthreads();

    {   // ---- Y = KT_ext @ U_ext + P2 @ H ; fold Dp*u skip; write y bf16
        bf16x8 Af[4][2];
        #pragma unroll
        for (int tt = 0; tt < 4; ++tt)
            #pragma unroll
            for (int jb = 0; jb < 2; ++jb)
                Af[tt][jb] = *reinterpret_cast<const bf16x8*>(
                    &KT_s[(tt * 16 + qm) * 64 + jb * 32 + qk * 8]);
        f32x4 acc[4][4] = {};
        #pragma unroll
        for (int kk = 0; kk < 4; ++kk)
            #pragma unroll
            for (int tt = 0; tt < 4; ++tt)
                #pragma unroll
                for (int ct = 0; ct < 4; ++ct)
                    acc[tt][ct] = __builtin_amdgcn_mfma_f32_16x16x32_bf16(
                        Af[tt][kk & 1], Uf[ct][kk], acc[tt][ct], 0, 0, 0);
        bf16x8 Pf[4][2];
        #pragma unroll
        for (int tt = 0; tt < 4; ++tt)
            #pragma unroll
            for (int kb = 0; kb < 2; ++kb)
                Pf[tt][kb] = *reinterpret_cast<const bf16x8*>(
                    &P2_s[(tt * 16 + qm) * 64 + kb * 32 + qk * 8]);
        #pragma unroll
        for (int ct = 0; ct < 4; ++ct)
            #pragma unroll
            for (int kb = 0; kb < 2; ++kb) {
                const bf16x8 Hf = *reinterpret_cast<const bf16x8*>(
                    &sh[(ct * 16 + qm) * 64 + kb * 32 + qk * 8]);
                #pragma unroll
                for (int tt = 0; tt < 4; ++tt)
                    acc[tt][ct] = __builtin_amdgcn_mfma_f32_16x16x32_bf16(
                        Pf[tt][kb], Hf, acc[tt][ct], 0, 0, 0);
            }
        // fold skip: read ALL u fp32 first (no overwrite yet)
        #pragma unroll
        for (int tt = 0; tt < 4; ++tt)
            #pragma unroll
            for (int ct = 0; ct < 4; ++ct) {
                const int c = ct * 16 + qm, t0 = tt * 16 + qk * 4;
                const float4 u4 = *reinterpret_cast<const float4*>(ug + c * 64 + t0);
                acc[tt][ct][0] += Dpd * u4.x;
                acc[tt][ct][1] += Dpd * u4.y;
                acc[tt][ct][2] += Dpd * u4.z;
                acc[tt][ct][3] += Dpd * u4.w;
            }
        __syncthreads();   // drain u reads before the bf16 overwrite of row halves
        u16* yb = reinterpret_cast<u16*>(ug);   // first 8KB of own 16KB row
        #pragma unroll
        for (int tt = 0; tt < 4; ++tt)
            #pragma unroll
            for (int ct = 0; ct < 4; ++ct) {
                const int c = ct * 16 + qm, t0 = tt * 16 + qk * 4;
                uint2 pk;
                pk.x = (u32)f2bf(acc[tt][ct][0]) | ((u32)f2bf(acc[tt][ct][1]) << 16);
                pk.y = (u32)f2bf(acc[tt][ct][2]) | ((u32)f2bf(acc[tt][ct][3]) << 16);
                *reinterpret_cast<uint2*>(&yb[c * 64 + t0]) = pk;
            }
    }
}

// ---------------------------------------------------------------------------
// transpose y bf16 [b][d][l] (packed in first half of ut rows, row stride
// 8192 u16) -> Ax rows [b*L][1024] bf16 for GEMM2. (verified R9)
// ---------------------------------------------------------------------------
__global__ __launch_bounds__(256) void trans_kernel(
    const float* __restrict__ yt, u16* __restrict__ Ax)
{
    __shared__ float T[64 * 68];
    const int b = blockIdx.z, dx = blockIdx.y * 64, lx = blockIdx.x * 64;
    const int tid = threadIdx.x;
    const int t16 = tid >> 4, l16 = tid & 15;
    const u16* yb = reinterpret_cast<const u16*>(yt);
    #pragma unroll
    for (int ii = 0; ii < 4; ++ii) {
        const int dd = ii * 16 + t16;
        const int ll = l16 * 4;
        const uint2 v = *reinterpret_cast<const uint2*>(
            &yb[((size_t)(b * D_MODEL + dx + dd)) * (SEQ * 2) + lx + ll]);
        *reinterpret_cast<float4*>(&T[dd * 68 + ll]) =
            make_float4(bf2f((u16)(v.x & 0xFFFFu)), bf2f((u16)(v.x >> 16)),
                        bf2f((u16)(v.y & 0xFFFFu)), bf2f((u16)(v.y >> 16)));
    }
    __syncthreads();
    #pragma unroll
    for (int ii = 0; ii < 4; ++ii) {
        const int ll = ii * 16 + t16;
        const int dd = l16 * 4;
        float v0 = T[(dd + 0) * 68 + ll], v1 = T[(dd + 1) * 68 + ll];
        float v2 = T[(dd + 2) * 68 + ll], v3 = T[(dd + 3) * 68 + ll];
        const size_t row = (size_t)b * SEQ + lx + ll;
        *reinterpret_cast<uint2*>(Ax + row * D_MODEL + dx + dd) =
            make_uint2((u32)f2bf(v0) | ((u32)f2bf(v1) << 16),
                       (u32)f2bf(v2) | ((u32)f2bf(v3) << 16));
    }
}

// ---------------------------------------------------------------------------
// Ledger (probes @185.6us baseline): g1+g2=53.6 (R12), prep+trans=18.3 (R13),
// scan2=24.2 (R15), fixed harness tax ~89.5us inside dur_us.
// GEMM structure experiments: 8-phase T-stack neutral (R4), 64x128/BK=32
// occupancy -10.5us (R17) -> 128x128/BK=64 is the shape-local optimum.
// This round: full revert to the R9-verified kernel (session best, 185.6us).
//
// Workspace (60 MB):
//   [0,  24MB)  Ax (16MB used)
//   [24, 56MB)  ut : [b][d][l] fp32 (scan writes y bf16 into row first-halves)
//   [56, 58MB)  Bw1 : Win bf16
//   [58, 60MB)  Bw2 : Wout bf16
// ---------------------------------------------------------------------------
extern "C" void kernel_launch(void* const* d_in, const int* in_sizes, int n_in,
                              void* d_out, int out_size, void* d_ws, size_t ws_size,
                              hipStream_t stream) {
    const float* x     = (const float*)d_in[0];
    const float* Win   = (const float*)d_in[1];
    const float* bin   = (const float*)d_in[2];
    const float* A_log = (const float*)d_in[3];
    const float* Bp    = (const float*)d_in[4];
    const float* Cp    = (const float*)d_in[5];
    const float* Dpv   = (const float*)d_in[6];
    const float* dtp   = (const float*)d_in[7];
    const float* Wout  = (const float*)d_in[8];
    const float* bout  = (const float*)d_in[9];
    float* out = (float*)d_out;

    char* ws = (char*)d_ws;
    u16*   Ax  = (u16*)(ws);
    float* ut  = (float*)(ws + (size_t)25165824);
    u16*   Bw1 = (u16*)(ws + (size_t)58720256);
    u16*   Bw2 = (u16*)(ws + (size_t)60817408);

    prep_kernel<<<2560, 256, 0, stream>>>(x, Win, Wout, Ax, Bw1, Bw2);
    gemm_bt<1><<<512, 256, 0, stream>>>(Ax, Bw1, bin, ut);
    scan2_kernel<<<D_MODEL, 128, 0, stream>>>(ut, A_log, Bp, Cp, dtp, Dpv);
    trans_kernel<<<dim3(SEQ / 64, D_MODEL / 64, BATCH), 256, 0, stream>>>(ut, Ax);
    gemm_bt<0><<<512, 256, 0, stream>>>(Ax, Bw2, bout, out);
}